// Round 12
// baseline (465.981 us; speedup 1.0000x reference)
//
#include <hip/hip_runtime.h>
#include <cstdint>
#include <cstddef>

typedef __bf16 bf16x8 __attribute__((ext_vector_type(8)));
typedef float f32x4 __attribute__((ext_vector_type(4)));

__device__ __forceinline__ float bf2f(unsigned short u){
  unsigned int x = ((unsigned int)u) << 16;
  return __builtin_bit_cast(float, x);
}
__device__ __forceinline__ unsigned short f2bf(float f){
  unsigned int x = __builtin_bit_cast(unsigned int, f);
  x += 0x7fffu + ((x >> 16) & 1u);
  return (unsigned short)(x >> 16);
}

// ---- DS-free cross-lane helpers: readlane (VALU) + DPP reductions ----
__device__ __forceinline__ int rl_i(int v, int l){ return __builtin_amdgcn_readlane(v, l); }
__device__ __forceinline__ float rl_f(float v, int l){
  return __builtin_bit_cast(float, __builtin_amdgcn_readlane(__builtin_bit_cast(int, v), l));
}
template<int C> __device__ __forceinline__ float dpp_add(float x){
  int y = __builtin_amdgcn_update_dpp(0, __builtin_bit_cast(int, x), C, 0xF, 0xF, true);
  return x + __builtin_bit_cast(float, y);
}
__device__ __forceinline__ float sum16(float x){
  x = dpp_add<0xB1>(x);    // quad_perm [1,0,3,2]
  x = dpp_add<0x4E>(x);    // quad_perm [2,3,0,1]
  x = dpp_add<0x124>(x);   // row_ror:4
  x = dpp_add<0x128>(x);   // row_ror:8
  return x;
}
__device__ __forceinline__ float sum64(float x){
  x = sum16(x);
  x = dpp_add<0x142>(x);   // row_bcast15
  x = dpp_add<0x143>(x);   // row_bcast31
  return rl_f(x, 63);
}

__device__ __forceinline__ float load_w(const void* ew, int e, int f){
  return f ? ((const float*)ew)[e] : bf2f(((const unsigned short*)ew)[e]);
}

// ---------------- mega canon kernel ----------------
// One launch: per-block dtype flag (256-short probe of x), param canon,
// weight transpose canon, x->bf16 canon, cnt zeroing.

struct MegaArgs {
  const void* psrc[15]; float* pdst[15]; int pn[15]; float pscale[15];
  const void* wsrc[6]; unsigned short* wdst[6]; int wM[6];
  const void* x; unsigned short* xc; int n4;
  int* cnt; int nz4;
  int* flag;
};

__global__ __launch_bounds__(256) void k_mega(MegaArgs a){
  __shared__ int sf;
  if (threadIdx.x == 0) sf = 0;
  __syncthreads();
  {
    unsigned short u = ((const unsigned short*)a.x)[threadIdx.x];
    int expo = (u >> 7) & 0xFF;
    if (expo >= 0xC0) atomicOr(&sf, 1);
  }
  __syncthreads();
  int f = sf;
  int b = blockIdx.x;

  if (b == 0){
    if (threadIdx.x == 0) a.flag[0] = f;
    for (int t = 0; t < 15; t++){
      int i = threadIdx.x;
      if (i < a.pn[t]){
        float v = f ? ((const float*)a.psrc[t])[i]
                    : bf2f(((const unsigned short*)a.psrc[t])[i]);
        a.pdst[t][i] = v * a.pscale[t];
      }
    }
    return;
  }
  b -= 1;
  if (b < 320){
    int t, base;
    if      (b <  64){ t = 0; base = b;       }
    else if (b < 128){ t = 1; base = b - 64;  }
    else if (b < 192){ t = 2; base = b - 128; }
    else if (b < 256){ t = 3; base = b - 192; }
    else if (b < 288){ t = 4; base = b - 256; }
    else             { t = 5; base = b - 288; }
    int M = a.wM[t];
    int idx = base*256 + threadIdx.x;
    if (idx < 128*M){
      int k = idx / M, m2 = idx % M;
      unsigned short v = f ? f2bf(((const float*)a.wsrc[t])[idx])
                           : ((const unsigned short*)a.wsrc[t])[idx];
      a.wdst[t][m2*128 + k] = v;
    }
    return;
  }
  b -= 320;
  int xB = (a.n4 + 255) / 256;
  if (b < xB){
    int i = b*256 + threadIdx.x;
    if (i < a.n4){
      if (f){
        float4 v = ((const float4*)a.x)[i];
        ushort4 o;
        o.x = f2bf(v.x); o.y = f2bf(v.y); o.z = f2bf(v.z); o.w = f2bf(v.w);
        ((ushort4*)a.xc)[i] = o;
      } else {
        ((ushort4*)a.xc)[i] = ((const ushort4*)a.x)[i];
      }
    }
    return;
  }
  b -= xB;
  int i = b*256 + threadIdx.x;
  if (i < a.nz4) ((int4*)a.cnt)[i] = make_int4(0, 0, 0, 0);
}

// ---------------- graph build ----------------

__global__ void k_hist(const int* __restrict__ ei, int* __restrict__ cnt,
                       int* __restrict__ rank, int E, int n){
  int e = blockIdx.x*256 + threadIdx.x;
  if (e < E){
    int d = ei[E + e];
    int r = 0;
    if ((unsigned)d < (unsigned)n) r = atomicAdd(&cnt[d], 1);
    rank[e] = r;
  }
}

// single-kernel exclusive scan of cnt -> rowptr (segments hold deg entries,
// self-loop handled inline by the edge kernels). Each block redundantly
// reduces cnt[0..b*256) (L2-hot) for its offset.
__global__ void k_scan(const int* __restrict__ cnt, int* __restrict__ rowptr, int n){
  int b = blockIdx.x, tid = threadIdx.x;
  int lane = tid & 63, w = tid >> 6;
  __shared__ int ws[4];
  __shared__ int sboff;

  int lim = b*256; if (lim > n) lim = n;
  int part = 0;
  for (int t = tid; t < lim; t += 256) part += cnt[t];
  for (int off = 32; off; off >>= 1) part += __shfl_down(part, off);
  if (lane == 0) ws[w] = part;
  __syncthreads();
  if (tid == 0) sboff = ws[0] + ws[1] + ws[2] + ws[3];
  __syncthreads();
  int boff = sboff;
  __syncthreads();

  int i = b*256 + tid;
  int v = (i < n) ? cnt[i] : 0;
  int sv = v;
  for (int off = 1; off < 64; off <<= 1){
    int t = __shfl_up(sv, off);
    if (lane >= off) sv += t;
  }
  if (lane == 63) ws[w] = sv;
  __syncthreads();
  if (tid == 0){
    int acc = 0;
    for (int k = 0; k < 4; k++){ int t = ws[k]; ws[k] = acc; acc += t; }
  }
  __syncthreads();
  if (i < n) rowptr[i + 1] = boff + ws[w] + sv;
  if (i == 0) rowptr[0] = 0;
}

// ATOMIC-FREE scatter: pos = rowptr[d] + rank[e]; one packed 8B store per edge
__global__ void k_scatter(const int* __restrict__ ei, const void* __restrict__ ew,
                          const int* __restrict__ rank, const int* __restrict__ rowptr,
                          uint2* __restrict__ csr,
                          int E, int n, const int* __restrict__ flag){
  int e = blockIdx.x*256 + threadIdx.x;
  if (e < E){
    int s = ei[e], d = ei[E + e];
    if ((unsigned)d < (unsigned)n){
      int pos = rowptr[d] + rank[e];
      if ((unsigned)pos < (unsigned)E){
        float w = load_w(ew, e, flag[0]);
        csr[pos] = make_uint2((unsigned)s, __builtin_bit_cast(unsigned, w));
      }
    }
  }
}

// ---------------- GEMM: xl (bf16 out) + xr (f32 out); 4 waves x 32 rows ----------------

template<int NC>
__global__ __launch_bounds__(256) void k_gemm2(
  const unsigned short* __restrict__ A,
  const unsigned short* __restrict__ WTl, const unsigned short* __restrict__ WTr,
  const float* __restrict__ bl, const float* __restrict__ br,
  unsigned short* __restrict__ outL, float* __restrict__ outR,
  int nrows)
{
  constexpr int CT = NC / 16;
  int tid = threadIdx.x;
  int wv = tid >> 6, lane = tid & 63;
  int q = lane >> 4, rr = lane & 15;
  int r0 = blockIdx.x * 128 + wv * 32;
  bool isR = blockIdx.y == 1;
  const unsigned short* WT = isR ? WTr : WTl;
  const float* bia         = isR ? br  : bl;

  f32x4 acc[2][CT];
  for (int a = 0; a < 2; a++)
    for (int b = 0; b < CT; b++)
      acc[a][b] = (f32x4){0.f, 0.f, 0.f, 0.f};

  for (int kc = 0; kc < 4; kc++){
    bf16x8 af[2], bfr[CT];
    #pragma unroll
    for (int rt = 0; rt < 2; rt++){
      int row = r0 + rt*16 + rr;
      if (row >= nrows) row = nrows - 1;
      af[rt] = *(const bf16x8*)(A + (size_t)row*128 + kc*32 + q*8);
    }
    #pragma unroll
    for (int ct = 0; ct < CT; ct++)
      bfr[ct] = *(const bf16x8*)(WT + (size_t)(ct*16 + rr)*128 + kc*32 + q*8);
    #pragma unroll
    for (int rt = 0; rt < 2; rt++)
      #pragma unroll
      for (int ct = 0; ct < CT; ct++)
        acc[rt][ct] = __builtin_amdgcn_mfma_f32_16x16x32_bf16(af[rt], bfr[ct], acc[rt][ct], 0, 0, 0);
  }

  // C/D layout: col = lane&15, row = (lane>>4)*4 + reg
  #pragma unroll
  for (int ct = 0; ct < CT; ct++){
    int col = ct*16 + rr;
    float bv = bia[col];
    #pragma unroll
    for (int rt = 0; rt < 2; rt++){
      #pragma unroll
      for (int t = 0; t < 4; t++){
        int row = r0 + rt*16 + q*4 + t;
        if (row < nrows){
          float v = acc[rt][ct][t] + bv;
          if (isR) outR[(size_t)row*NC + col] = v;
          else     outL[(size_t)row*NC + col] = f2bf(v);
        }
      }
    }
  }
}

// ---------------- fused edge scoring + online-softmax aggregation ----------------
// DS-free (readlane + DPP); exp2 softmax (att pre-scaled by log2e); 8-wide
// unroll; self-loop computed inline (wsum accumulated from the edges read).

__global__ __launch_bounds__(256) void k_edge128(
  const unsigned short* __restrict__ xl, const float* __restrict__ xr,
  const int* __restrict__ rowptr, const uint2* __restrict__ csr,
  const float* __restrict__ We, const float* __restrict__ att,
  const float* __restrict__ bias, unsigned short* __restrict__ out, int n, int E)
{
  int wid = threadIdx.x >> 6;
  int lane = threadIdx.x & 63;
  int node = blockIdx.x*4 + wid;
  if (node >= n) return;
  int ch = lane*2;
  float we0 = We[ch],  we1 = We[ch+1];
  float at0 = att[ch], at1 = att[ch+1];   // pre-scaled by log2e
  float2 xrv = *(const float2*)(xr + (size_t)node*128 + ch);
  float fxr0 = xrv.x, fxr1 = xrv.y;
  const unsigned short* xlc = xl + ch;
  int beg = rowptr[node], end = rowptr[node+1];
  if (beg < 0) beg = 0;
  if (end > E) end = E;
  float m = -1e30f, l = 0.f, a0 = 0.f, a1 = 0.f;
  float ws_tot = 0.f;

  for (int base = beg; base < end; base += 64){
    int idx = base + lane;
    int   sv = 0; float wv = 0.f;
    if (idx < end){
      uint2 pk = csr[idx];
      sv = (int)pk.x;
      wv = __builtin_bit_cast(float, pk.y);
    }
    if ((unsigned)sv >= (unsigned)n) sv = 0;
    ws_tot += sum64(wv);
    int c = end - base; if (c > 64) c = 64;
    int i = 0;
    for (; i + 8 <= c; i += 8){
      unsigned int u[8]; float w[8];
      #pragma unroll
      for (int j = 0; j < 8; j++){
        int s = rl_i(sv, i + j);
        w[j] = rl_f(wv, i + j);
        u[j] = *(const unsigned int*)(xlc + (size_t)s*128);
      }
      float vx[8], vy[8], pp[8];
      #pragma unroll
      for (int j = 0; j < 8; j++){
        vx[j] = __builtin_bit_cast(float, u[j] << 16);
        vy[j] = __builtin_bit_cast(float, u[j] & 0xffff0000u);
        float t0 = vx[j] + fxr0 + w[j]*we0;
        float t1 = vy[j] + fxr1 + w[j]*we1;
        t0 = fmaxf(t0, 0.2f*t0);
        t1 = fmaxf(t1, 0.2f*t1);
        pp[j] = sum16(t0*at0 + t1*at1);
      }
      float mx = fmaxf(fmaxf(fmaxf(pp[0], pp[1]), fmaxf(pp[2], pp[3])),
                       fmaxf(fmaxf(pp[4], pp[5]), fmaxf(pp[6], pp[7])));
      float nm = fmaxf(m, mx);
      float sc = exp2f(m - nm);
      float el = 0.f, ea0 = 0.f, ea1 = 0.f;
      #pragma unroll
      for (int j = 0; j < 8; j++){
        float e = exp2f(pp[j] - nm);
        el  += e;
        ea0 += e*vx[j];
        ea1 += e*vy[j];
      }
      l  = l*sc  + el;
      a0 = a0*sc + ea0;
      a1 = a1*sc + ea1;
      m = nm;
    }
    for (; i < c; i++){
      int   s = rl_i(sv, i);
      float w = rl_f(wv, i);
      unsigned int u = *(const unsigned int*)(xlc + (size_t)s*128);
      float x0 = __builtin_bit_cast(float, u << 16);
      float x1 = __builtin_bit_cast(float, u & 0xffff0000u);
      float t0 = x0 + fxr0 + w*we0;
      float t1 = x1 + fxr1 + w*we1;
      t0 = fmaxf(t0, 0.2f*t0);
      t1 = fmaxf(t1, 0.2f*t1);
      float p = sum16(t0*at0 + t1*at1);
      float nm = fmaxf(m, p);
      float sc = exp2f(m - nm);
      float pe = exp2f(p - nm);
      l  = l*sc  + pe;
      a0 = a0*sc + pe*x0;
      a1 = a1*sc + pe*x1;
      m = nm;
    }
  }
  // inline self-loop: src = node, w = mean incoming weight
  {
    int deg = end - beg;
    float wsf = ws_tot / fmaxf((float)deg, 1.0f);
    unsigned int u = *(const unsigned int*)(xlc + (size_t)node*128);
    float x0 = __builtin_bit_cast(float, u << 16);
    float x1 = __builtin_bit_cast(float, u & 0xffff0000u);
    float t0 = x0 + fxr0 + wsf*we0;
    float t1 = x1 + fxr1 + wsf*we1;
    t0 = fmaxf(t0, 0.2f*t0);
    t1 = fmaxf(t1, 0.2f*t1);
    float p = sum16(t0*at0 + t1*at1);
    float nm = fmaxf(m, p);
    float sc = exp2f(m - nm);
    float pe = exp2f(p - nm);
    l  = l*sc  + pe;
    a0 = a0*sc + pe*x0;
    a1 = a1*sc + pe*x1;
  }
  float inv = 1.0f / (l + 1e-16f);
  float o0 = a0*inv + bias[ch];
  float o1 = a1*inv + bias[ch+1];
  o0 = o0 > 0.f ? o0 : (__expf(o0) - 1.0f);   // ELU (layers 0,1)
  o1 = o1 > 0.f ? o1 : (__expf(o1) - 1.0f);
  unsigned int packed = (unsigned int)f2bf(o0) | ((unsigned int)f2bf(o1) << 16);
  *(unsigned int*)(out + (size_t)node*128 + ch) = packed;
}

__global__ __launch_bounds__(256) void k_edge64(
  const unsigned short* __restrict__ xl, const float* __restrict__ xr,
  const int* __restrict__ rowptr, const uint2* __restrict__ csr,
  const float* __restrict__ We, const float* __restrict__ att,
  const float* __restrict__ bias, void* __restrict__ out, int n, int E,
  const int* __restrict__ flag)
{
  int wid = threadIdx.x >> 6;
  int lane = threadIdx.x & 63;
  int node = blockIdx.x*4 + wid;
  if (node >= n) return;
  float we0 = We[lane];
  float at0 = att[lane];          // pre-scaled by log2e
  float fxr0 = xr[(size_t)node*64 + lane];
  const unsigned short* xlc = xl + lane;
  int beg = rowptr[node], end = rowptr[node+1];
  if (beg < 0) beg = 0;
  if (end > E) end = E;
  float m = -1e30f, l = 0.f, a0 = 0.f;
  float ws_tot = 0.f;

  for (int base = beg; base < end; base += 64){
    int idx = base + lane;
    int   sv = 0; float wv = 0.f;
    if (idx < end){
      uint2 pk = csr[idx];
      sv = (int)pk.x;
      wv = __builtin_bit_cast(float, pk.y);
    }
    if ((unsigned)sv >= (unsigned)n) sv = 0;
    ws_tot += sum64(wv);
    int c = end - base; if (c > 64) c = 64;
    int i = 0;
    for (; i + 8 <= c; i += 8){
      float x[8], w[8], pp[8];
      #pragma unroll
      for (int j = 0; j < 8; j++){
        int s = rl_i(sv, i + j);
        w[j] = rl_f(wv, i + j);
        x[j] = bf2f(xlc[(size_t)s*64]);
      }
      #pragma unroll
      for (int j = 0; j < 8; j++){
        float t = x[j] + fxr0 + w[j]*we0;
        t = fmaxf(t, 0.2f*t);
        pp[j] = sum64(t*at0);
      }
      float mx = fmaxf(fmaxf(fmaxf(pp[0], pp[1]), fmaxf(pp[2], pp[3])),
                       fmaxf(fmaxf(pp[4], pp[5]), fmaxf(pp[6], pp[7])));
      float nm = fmaxf(m, mx);
      float sc = exp2f(m - nm);
      float el = 0.f, ea = 0.f;
      #pragma unroll
      for (int j = 0; j < 8; j++){
        float e = exp2f(pp[j] - nm);
        el += e;
        ea += e*x[j];
      }
      l  = l*sc  + el;
      a0 = a0*sc + ea;
      m = nm;
    }
    for (; i < c; i++){
      int   s = rl_i(sv, i);
      float w = rl_f(wv, i);
      float x0 = bf2f(xlc[(size_t)s*64]);
      float t0 = x0 + fxr0 + w*we0;
      t0 = fmaxf(t0, 0.2f*t0);
      float p = sum64(t0*at0);
      float nm = fmaxf(m, p);
      float sc = exp2f(m - nm);
      float pe = exp2f(p - nm);
      l  = l*sc  + pe;
      a0 = a0*sc + pe*x0;
      m = nm;
    }
  }
  // inline self-loop
  {
    int deg = end - beg;
    float wsf = ws_tot / fmaxf((float)deg, 1.0f);
    float x0 = bf2f(xlc[(size_t)node*64]);
    float t0 = x0 + fxr0 + wsf*we0;
    t0 = fmaxf(t0, 0.2f*t0);
    float p = sum64(t0*at0);
    float nm = fmaxf(m, p);
    float sc = exp2f(m - nm);
    float pe = exp2f(p - nm);
    l  = l*sc  + pe;
    a0 = a0*sc + pe*x0;
  }
  float inv = 1.0f / (l + 1e-16f);
  float res = a0*inv + bias[lane];
  size_t oi = (size_t)node*64 + lane;
  if (flag[0]) ((float*)out)[oi] = res;
  else         ((unsigned short*)out)[oi] = f2bf(res);
}

// ---------------- host ----------------

extern "C" void kernel_launch(void* const* d_in, const int* in_sizes, int n_in,
                              void* d_out, int out_size, void* d_ws, size_t ws_size,
                              hipStream_t stream)
{
  (void)n_in; (void)out_size; (void)ws_size;
  const void* x   = d_in[0];
  const int*  ei  = (const int*)d_in[1];
  const void* ew  = d_in[2];

  const int N = in_sizes[0] / 128;
  const int E = in_sizes[2];
  const int nB = (N + 255) / 256;

  char* p = (char*)d_ws;
  size_t off = 0;
  auto carve = [&](size_t bytes)->void* {
    void* r = p + off;
    off = (off + bytes + 255) & ~(size_t)255;
    return r;
  };
  int*            flag    = (int*)carve(4);
  int*            cnt     = (int*)carve((size_t)((N+3)/4)*16);
  int*            rowptr  = (int*)carve((size_t)(N+1)*4);
  int*            rank    = (int*)carve((size_t)E*4);
  uint2*          csr     = (uint2*)carve((size_t)E*8);
  float*          prm     = (float*)carve(15*128*4);
  unsigned short* WT0l    = (unsigned short*)carve(128*128*2);
  unsigned short* WT0r    = (unsigned short*)carve(128*128*2);
  unsigned short* WT1l    = (unsigned short*)carve(128*128*2);
  unsigned short* WT1r    = (unsigned short*)carve(128*128*2);
  unsigned short* WT2l    = (unsigned short*)carve(128*64*2);
  unsigned short* WT2r    = (unsigned short*)carve(128*64*2);
  unsigned short* xc      = (unsigned short*)carve((size_t)N*128*2);
  unsigned short* xlb16   = (unsigned short*)carve((size_t)N*128*2);
  float*          xrb     = (float*)carve((size_t)N*128*4);
  unsigned short* hb      = (unsigned short*)carve((size_t)N*128*2);

  float* bl0c = prm + 0*128;  float* br0c = prm + 1*128;
  float* We0c = prm + 2*128;  float* at0c = prm + 3*128;  float* bi0c = prm + 4*128;
  float* bl1c = prm + 5*128;  float* br1c = prm + 6*128;
  float* We1c = prm + 7*128;  float* at1c = prm + 8*128;  float* bi1c = prm + 9*128;
  float* bl2c = prm + 10*128; float* br2c = prm + 11*128;
  float* We2c = prm + 12*128; float* at2c = prm + 13*128; float* bi2c = prm + 14*128;

  const float LOG2E = 1.4426950408889634f;
  MegaArgs ma;
  {
    const void* srcs[15] = { d_in[4], d_in[6], d_in[7], d_in[8], d_in[9],
                             d_in[11], d_in[13], d_in[14], d_in[15], d_in[16],
                             d_in[18], d_in[20], d_in[21], d_in[22], d_in[23] };
    float* dsts[15] = { bl0c, br0c, We0c, at0c, bi0c,
                        bl1c, br1c, We1c, at1c, bi1c,
                        bl2c, br2c, We2c, at2c, bi2c };
    int ns[15] = {128,128,128,128,128, 128,128,128,128,128, 64,64,64,64,64};
    for (int i = 0; i < 15; i++){
      ma.psrc[i] = srcs[i]; ma.pdst[i] = dsts[i]; ma.pn[i] = ns[i];
      ma.pscale[i] = (i == 3 || i == 8 || i == 13) ? LOG2E : 1.0f;  // att slots
    }
    const void* wsrcs[6] = { d_in[3], d_in[5], d_in[10], d_in[12], d_in[17], d_in[19] };
    unsigned short* wdsts[6] = { WT0l, WT0r, WT1l, WT1r, WT2l, WT2r };
    int Ms[6] = {128, 128, 128, 128, 64, 64};
    for (int i = 0; i < 6; i++){ ma.wsrc[i] = wsrcs[i]; ma.wdst[i] = wdsts[i]; ma.wM[i] = Ms[i]; }
    ma.x = x; ma.xc = xc; ma.n4 = N*32;
    ma.cnt = cnt; ma.nz4 = (N + 3) / 4;
    ma.flag = flag;
  }
  int xB = (ma.n4 + 255) / 256;
  int zB = (ma.nz4 + 255) / 256;
  k_mega<<<1 + 320 + xB + zB, 256, 0, stream>>>(ma);

  // graph build: hist (1 atomic/edge + rank), single-kernel scan, atomic-free scatter
  k_hist <<<(E+255)/256, 256, 0, stream>>>(ei, cnt, rank, E, N);
  k_scan <<<nB, 256, 0, stream>>>(cnt, rowptr, N);
  k_scatter<<<(E+255)/256, 256, 0, stream>>>(ei, ew, rank, rowptr, csr, E, N, flag);

  const int rowBlocks = (N + 127) / 128;

  // layer 0
  k_gemm2<128><<<dim3(rowBlocks, 2), 256, 0, stream>>>(xc, WT0l, WT0r, bl0c, br0c, xlb16, xrb, N);
  k_edge128<<<(N+3)/4, 256, 0, stream>>>(xlb16, xrb, rowptr, csr, We0c, at0c, bi0c, hb, N, E);

  // layer 1
  k_gemm2<128><<<dim3(rowBlocks, 2), 256, 0, stream>>>(hb, WT1l, WT1r, bl1c, br1c, xlb16, xrb, N);
  k_edge128<<<(N+3)/4, 256, 0, stream>>>(xlb16, xrb, rowptr, csr, We1c, at1c, bi1c, hb, N, E);

  // layer 2
  k_gemm2<64><<<dim3(rowBlocks, 2), 256, 0, stream>>>(hb, WT2l, WT2r, bl2c, br2c, xlb16, xrb, N);
  k_edge64<<<(N+3)/4, 256, 0, stream>>>(xlb16, xrb, rowptr, csr, We2c, at2c, bi2c,
                                        d_out, N, E, flag);
}